// Round 3
// baseline (2287.911 us; speedup 1.0000x reference)
//
#include <hip/hip_runtime.h>

typedef float f32x4 __attribute__((ext_vector_type(4)));
typedef __bf16 bf16x8 __attribute__((ext_vector_type(8)));

#define NSTAGE 20
#define TSEQ   2048
#define NST    128
#define NP2    256
#define NCLS   202

static __device__ __forceinline__ unsigned short f2b(float f) {
  return __builtin_bit_cast(unsigned short, (__bf16)f);
}

// ---------------------------------------------------------------------------
// Kernel 1: convert weights to bf16 in ws, with MFMA-friendly layouts.
//  Wt   [64][2048]  = W_embed^T
//  Bws  [20][256][64]: row n'=2n+p holds B_{re/im}[s][n][k] along k
//  Cws  [20][64][256]: row d holds (C_re[s][d][n], -C_im[s][d][n]) interleaved
//  Wclst[208][64]   = W_cls^T, rows >=202 zero
// ---------------------------------------------------------------------------
__global__ void lru_convert_kernel(const float* __restrict__ Wemb,
                                   const float* __restrict__ Bre, const float* __restrict__ Bim,
                                   const float* __restrict__ Cre, const float* __restrict__ Cim,
                                   const float* __restrict__ Wcls,
                                   unsigned short* __restrict__ Wt,
                                   unsigned short* __restrict__ Bws,
                                   unsigned short* __restrict__ Cws,
                                   unsigned short* __restrict__ Wclst)
{
  const int NWT = 64 * 2048;          // 131072
  const int NB  = NSTAGE * NP2 * 64;  // 327680
  const int NC  = NSTAGE * 64 * NP2;  // 327680
  const int NWC = 208 * 64;           // 13312
  int idx = blockIdx.x * 256 + threadIdx.x;
  if (idx < NWT) {
    int d = idx >> 11, k = idx & 2047;
    Wt[idx] = f2b(Wemb[k * 64 + d]);
  } else if (idx < NWT + NB) {
    int r = idx - NWT;
    int s = r / (NP2 * 64); int r2 = r % (NP2 * 64);
    int np = r2 >> 6, k = r2 & 63;
    int n = np >> 1, p = np & 1;
    float v = p ? Bim[(s * NST + n) * 64 + k] : Bre[(s * NST + n) * 64 + k];
    Bws[r] = f2b(v);
  } else if (idx < NWT + NB + NC) {
    int r = idx - NWT - NB;
    int s = r / (64 * NP2); int r2 = r % (64 * NP2);
    int d = r2 >> 8, np = r2 & 255;
    int n = np >> 1, p = np & 1;
    float v = p ? -Cim[(s * 64 + d) * NST + n] : Cre[(s * 64 + d) * NST + n];
    Cws[r] = f2b(v);
  } else if (idx < NWT + NB + NC + NWC) {
    int r = idx - NWT - NB - NC;
    int cls = r >> 6, k = r & 63;
    Wclst[r] = (cls < NCLS) ? f2b(Wcls[k * NCLS + cls]) : (unsigned short)0;
  }
}

// ---------------------------------------------------------------------------
// Fused persistent kernel (plain launch, NO cooperative groups, NO grid
// barrier). Block (b,c) owns tokens [c*16, c*16+16) of batch b for the whole
// network; h lives in LDS. Cross-block dependency is only backward in c:
// stage-s prefix of chunk c needs stage-s local carries of chunks j<c.
// Decoupled lookback: carries are versioned per stage (no WAR reuse) and
// published with an agent-scope release flag; readers spin with acquire
// loads. Dependencies point strictly to lower blockIdx -> deadlock-free
// under in-order dispatch regardless of residency.
// ---------------------------------------------------------------------------
__launch_bounds__(256)
__global__ void lru_fused_kernel(
    const float* __restrict__ x,
    const float* __restrict__ ln0g, const float* __restrict__ ln0b,
    const unsigned short* __restrict__ Wt, const float* __restrict__ bemb,
    const unsigned short* __restrict__ Bws, const unsigned short* __restrict__ Cws,
    const float* __restrict__ lng, const float* __restrict__ lnb,
    const float* __restrict__ nulog, const float* __restrict__ thlog,
    const float* __restrict__ gmlog, const float* __restrict__ dskip,
    const unsigned short* __restrict__ Wclst, const float* __restrict__ bcls,
    float* __restrict__ carr, unsigned* __restrict__ flags,
    float* __restrict__ out)
{
  __shared__ float hsm[16][68];
  __shared__ float zsm[16][68];
  __shared__ __align__(16) unsigned short zb[16][72];
  __shared__ __align__(16) float ucat[16][264];
  __shared__ __align__(16) unsigned short hcb[16][264];
  __shared__ float mu_s[16], rs_s[16];

  const int tid = threadIdx.x;
  const int b = blockIdx.x >> 7;
  const int c = blockIdx.x & 127;
  const int t0 = c * 16;
  const int w = tid >> 6, lane = tid & 63;
  const int cl = lane & 15, q = lane >> 4;
  const int tg = tid >> 4, g = tid & 15;

  // ---- Phase E0: LN0 statistics (wave w -> tokens 4w..4w+3) ----
  for (int i = 0; i < 4; ++i) {
    int t = w * 4 + i;
    const float* xp = x + ((size_t)(b * TSEQ + t0 + t)) * 2048;
    float sum = 0.f, sq = 0.f;
    #pragma unroll
    for (int j = 0; j < 32; ++j) {
      float v = xp[lane + 64 * j];
      sum += v; sq += v * v;
    }
    #pragma unroll
    for (int m = 1; m < 64; m <<= 1) {
      sum += __shfl_xor(sum, m); sq += __shfl_xor(sq, m);
    }
    if (lane == 0) {
      float mu = sum * (1.f / 2048.f);
      float var = sq * (1.f / 2048.f) - mu * mu;
      mu_s[t] = mu;
      rs_s[t] = rsqrtf(var + 1e-5f);
    }
  }
  __syncthreads();

  // ---- Phase E1: embed GEMM (16 tok x 2048 @ 2048 x 64) -> hsm ----
  {
    const int st = tg;          // staging token 0..15
    const int g4 = g * 4;       // k offset within 64-chunk
    const float muT = mu_s[st], rsT = rs_s[st];
    f32x4 acc = {0.f, 0.f, 0.f, 0.f};
    for (int kc = 0; kc < 32; ++kc) {
      __syncthreads();
      {
        const float* xp = x + ((size_t)(b * TSEQ + t0 + st)) * 2048 + kc * 64 + g4;
        float4 xv = *(const float4*)xp;
        float4 gv = *(const float4*)&ln0g[kc * 64 + g4];
        float4 bv = *(const float4*)&ln0b[kc * 64 + g4];
        float z0 = (xv.x - muT) * rsT * gv.x + bv.x;
        float z1 = (xv.y - muT) * rsT * gv.y + bv.y;
        float z2 = (xv.z - muT) * rsT * gv.z + bv.z;
        float z3 = (xv.w - muT) * rsT * gv.w + bv.w;
        *(unsigned*)&zb[st][g4]     = (unsigned)f2b(z0) | ((unsigned)f2b(z1) << 16);
        *(unsigned*)&zb[st][g4 + 2] = (unsigned)f2b(z2) | ((unsigned)f2b(z3) << 16);
      }
      __syncthreads();
      bf16x8 a0 = *(const bf16x8*)((const char*)&zb[0][0] + cl * 144 + q * 16);
      bf16x8 a1 = *(const bf16x8*)((const char*)&zb[0][0] + cl * 144 + 64 + q * 16);
      const unsigned short* wp = Wt + ((size_t)(w * 16 + cl)) * 2048 + kc * 64 + q * 8;
      bf16x8 w0 = *(const bf16x8*)wp;
      bf16x8 w1 = *(const bf16x8*)(wp + 32);
      acc = __builtin_amdgcn_mfma_f32_16x16x32_bf16(a0, w0, acc, 0, 0, 0);
      acc = __builtin_amdgcn_mfma_f32_16x16x32_bf16(a1, w1, acc, 0, 0, 0);
    }
    int d = w * 16 + cl;
    float be = bemb[d];
    #pragma unroll
    for (int r = 0; r < 4; ++r) hsm[q * 4 + r][d] = acc[r] + be;
  }
  __syncthreads();

  // ---- Stage loop ----
  for (int s = 0; s < NSTAGE; ++s) {
    float* carr_s = carr + ((size_t)(s * 8 + b)) * 128 * 256;
    unsigned* flag_s = flags + (size_t)(s * 8 + b) * 128;

    // LayerNorm over D=64 from hsm (16-lane subgroup per token)
    {
      float4 hv = *(const float4*)&hsm[tg][g * 4];
      float sum = hv.x + hv.y + hv.z + hv.w;
      sum += __shfl_xor(sum, 1); sum += __shfl_xor(sum, 2);
      sum += __shfl_xor(sum, 4); sum += __shfl_xor(sum, 8);
      float mu = sum * (1.f / 64.f);
      float d0 = hv.x - mu, d1 = hv.y - mu, d2 = hv.z - mu, d3 = hv.w - mu;
      float sq = d0 * d0 + d1 * d1 + d2 * d2 + d3 * d3;
      sq += __shfl_xor(sq, 1); sq += __shfl_xor(sq, 2);
      sq += __shfl_xor(sq, 4); sq += __shfl_xor(sq, 8);
      float rs = rsqrtf(sq * (1.f / 64.f) + 1e-5f);
      float4 gv = *(const float4*)&lng[s * 64 + g * 4];
      float4 bv = *(const float4*)&lnb[s * 64 + g * 4];
      float z0 = d0 * rs * gv.x + bv.x;
      float z1 = d1 * rs * gv.y + bv.y;
      float z2 = d2 * rs * gv.z + bv.z;
      float z3 = d3 * rs * gv.w + bv.w;
      zsm[tg][g * 4 + 0] = z0; zsm[tg][g * 4 + 1] = z1;
      zsm[tg][g * 4 + 2] = z2; zsm[tg][g * 4 + 3] = z3;
      *(unsigned*)&zb[tg][g * 4]     = (unsigned)f2b(z0) | ((unsigned)f2b(z1) << 16);
      *(unsigned*)&zb[tg][g * 4 + 2] = (unsigned)f2b(z2) | ((unsigned)f2b(z3) << 16);
    }
    __syncthreads();

    // U = Z * B^T scaled by gamma (MFMA)
    {
      bf16x8 a0 = *(const bf16x8*)((const char*)&zb[0][0] + cl * 144 + q * 16);
      bf16x8 a1 = *(const bf16x8*)((const char*)&zb[0][0] + cl * 144 + 64 + q * 16);
      const unsigned short* bb = Bws + (size_t)s * NP2 * 64;
      #pragma unroll
      for (int ti = 0; ti < 4; ++ti) {
        int np0 = (w * 4 + ti) * 16;
        const unsigned short* bp = bb + (np0 + cl) * 64 + q * 8;
        bf16x8 b0 = *(const bf16x8*)bp;
        bf16x8 b1 = *(const bf16x8*)(bp + 32);
        f32x4 acc = {0.f, 0.f, 0.f, 0.f};
        acc = __builtin_amdgcn_mfma_f32_16x16x32_bf16(a0, b0, acc, 0, 0, 0);
        acc = __builtin_amdgcn_mfma_f32_16x16x32_bf16(a1, b1, acc, 0, 0, 0);
        int np = np0 + cl;
        float gam = __expf(gmlog[s * NST + (np >> 1)]);
        ucat[q * 4 + 0][np] = acc[0] * gam;
        ucat[q * 4 + 1][np] = acc[1] * gam;
        ucat[q * 4 + 2][np] = acc[2] * gam;
        ucat[q * 4 + 3][np] = acc[3] * gam;
      }
    }
    __syncthreads();

    // local 16-step scan (in place) + carry write to this stage's buffer
    float lamr = 0.f, lami = 0.f, ar = 0.f, ai = 0.f;
    if (tid < NST) {
      int n = tid;
      float mag = __expf(-__expf(nulog[s * NST + n]));
      float th  = __expf(thlog[s * NST + n]);
      lamr = mag * __cosf(th);
      lami = mag * __sinf(th);
      float hr = 0.f, hi = 0.f;
      #pragma unroll
      for (int t = 0; t < 16; ++t) {
        float ur = ucat[t][2 * n], ui = ucat[t][2 * n + 1];
        float nr = fmaf(lamr, hr, fmaf(-lami, hi, ur));
        float ni = fmaf(lamr, hi, fmaf(lami, hr, ui));
        hr = nr; hi = ni;
        ucat[t][2 * n] = hr; ucat[t][2 * n + 1] = hi;
      }
      float* cw = carr_s + (size_t)c * 256 + 2 * n;
      cw[0] = hr;
      cw[1] = hi;
      // lam^16
      ar = lamr; ai = lami;
      #pragma unroll
      for (int it = 0; it < 4; ++it) {
        float nr = ar * ar - ai * ai;
        float ni = 2.f * ar * ai;
        ar = nr; ai = ni;
      }
    }
    __syncthreads();

    // publish this chunk's carry (release), then wait for predecessors
    if (tid == 0) {
      __builtin_amdgcn_fence(__ATOMIC_RELEASE, "agent");
      __hip_atomic_store(&flag_s[c], 1u, __ATOMIC_RELEASE, __HIP_MEMORY_SCOPE_AGENT);
    }
    if (tid < c) {
      while (__hip_atomic_load(&flag_s[tid], __ATOMIC_ACQUIRE,
                               __HIP_MEMORY_SCOPE_AGENT) == 0u) {
        __builtin_amdgcn_s_sleep(1);
      }
    }
    __syncthreads();
    __builtin_amdgcn_fence(__ATOMIC_ACQUIRE, "agent");

    // prefix over earlier chunks + apply -> hcb (bf16)
    if (tid < NST) {
      int n = tid;
      float Pr = 0.f, Pi = 0.f;
      const float* cb = carr_s + 2 * n;
      for (int j = 0; j < c; ++j) {
        float cr = cb[j * 256];
        float ci = cb[j * 256 + 1];
        float nr = fmaf(ar, Pr, fmaf(-ai, Pi, cr));
        float ni = fmaf(ar, Pi, fmaf(ai, Pr, ci));
        Pr = nr; Pi = ni;
      }
      float mr = lamr, mi = lami;
      #pragma unroll
      for (int t = 0; t < 16; ++t) {
        float hgr = ucat[t][2 * n]     + mr * Pr - mi * Pi;
        float hgi = ucat[t][2 * n + 1] + mr * Pi + mi * Pr;
        *(unsigned*)&hcb[t][2 * n] = (unsigned)f2b(hgr) | ((unsigned)f2b(hgi) << 16);
        float nmr = mr * lamr - mi * lami;
        float nmi = mr * lami + mi * lamr;
        mr = nmr; mi = nmi;
      }
    }
    __syncthreads();

    // Y = Hcat * Cc (MFMA, K=256); h += y + Dskip*z  (in LDS)
    {
      int d0 = w * 16;
      const unsigned short* cp = Cws + ((size_t)s * 64 + d0 + cl) * NP2 + q * 8;
      f32x4 acc = {0.f, 0.f, 0.f, 0.f};
      #pragma unroll
      for (int ks = 0; ks < 8; ++ks) {
        bf16x8 a  = *(const bf16x8*)((const char*)&hcb[0][0] + cl * 528 + ks * 64 + q * 16);
        bf16x8 cc = *(const bf16x8*)(cp + ks * 32);
        acc = __builtin_amdgcn_mfma_f32_16x16x32_bf16(a, cc, acc, 0, 0, 0);
      }
      int d = d0 + cl;
      float dk = dskip[s * 64 + d];
      #pragma unroll
      for (int r = 0; r < 4; ++r) {
        int t = q * 4 + r;
        hsm[t][d] = hsm[t][d] + acc[r] + dk * zsm[t][d];
      }
    }
    __syncthreads();
  }

  // ---- Classifier: out = h @ W_cls + b_cls ----
  {
    *(unsigned*)&zb[tg][g * 4] =
        (unsigned)f2b(hsm[tg][g * 4 + 0]) | ((unsigned)f2b(hsm[tg][g * 4 + 1]) << 16);
    *(unsigned*)&zb[tg][g * 4 + 2] =
        (unsigned)f2b(hsm[tg][g * 4 + 2]) | ((unsigned)f2b(hsm[tg][g * 4 + 3]) << 16);
  }
  __syncthreads();
  {
    bf16x8 a0 = *(const bf16x8*)((const char*)&zb[0][0] + cl * 144 + q * 16);
    bf16x8 a1 = *(const bf16x8*)((const char*)&zb[0][0] + cl * 144 + 64 + q * 16);
    for (int ti = w; ti < 13; ti += 4) {
      int cls0 = ti * 16;
      const unsigned short* wp = Wclst + (cls0 + cl) * 64 + q * 8;
      bf16x8 b0 = *(const bf16x8*)wp;
      bf16x8 b1 = *(const bf16x8*)(wp + 32);
      f32x4 acc = {0.f, 0.f, 0.f, 0.f};
      acc = __builtin_amdgcn_mfma_f32_16x16x32_bf16(a0, b0, acc, 0, 0, 0);
      acc = __builtin_amdgcn_mfma_f32_16x16x32_bf16(a1, b1, acc, 0, 0, 0);
      int cls = cls0 + cl;
      if (cls < NCLS) {
        float bc = bcls[cls];
        #pragma unroll
        for (int r = 0; r < 4; ++r) {
          int t = q * 4 + r;
          out[((size_t)(b * TSEQ + t0 + t)) * NCLS + cls] = acc[r] + bc;
        }
      }
    }
  }
}

// ---------------------------------------------------------------------------
extern "C" void kernel_launch(void* const* d_in, const int* in_sizes, int n_in,
                              void* d_out, int out_size, void* d_ws, size_t ws_size,
                              hipStream_t stream) {
  (void)in_sizes; (void)n_in; (void)out_size; (void)ws_size;
  const float* x     = (const float*)d_in[0];
  const float* ln0g  = (const float*)d_in[1];
  const float* ln0b  = (const float*)d_in[2];
  const float* Wemb  = (const float*)d_in[3];
  const float* bemb  = (const float*)d_in[4];
  const float* lng   = (const float*)d_in[5];
  const float* lnb   = (const float*)d_in[6];
  const float* nulog = (const float*)d_in[7];
  const float* thlog = (const float*)d_in[8];
  const float* gmlog = (const float*)d_in[9];
  const float* Bre   = (const float*)d_in[10];
  const float* Bim   = (const float*)d_in[11];
  const float* Cre   = (const float*)d_in[12];
  const float* Cim   = (const float*)d_in[13];
  const float* dskip = (const float*)d_in[14];
  const float* Wcls  = (const float*)d_in[15];
  const float* bcls  = (const float*)d_in[16];
  float* out = (float*)d_out;

  char* ws = (char*)d_ws;
  // ws layout (bytes):
  //  carr  @0        : 20*8*128*256*4 = 20971520   (per-stage carries)
  //  flags @20971520 : 20*8*128*4     = 81920
  //  Bws   @21053440 : 20*256*64*2    = 655360
  //  Cws   @21708800 : 655360
  //  Wt    @22364160 : 64*2048*2     = 262144
  //  Wclst @22626304 : 208*64*2      = 26624      (end 22652928)
  float* carr          = (float*)(ws + 0);
  unsigned* flags      = (unsigned*)(ws + 20971520);
  unsigned short* Bws  = (unsigned short*)(ws + 21053440);
  unsigned short* Cws  = (unsigned short*)(ws + 21708800);
  unsigned short* Wt   = (unsigned short*)(ws + 22364160);
  unsigned short* Wcl  = (unsigned short*)(ws + 22626304);

  (void)hipMemsetAsync(flags, 0, 20 * 8 * 128 * sizeof(unsigned), stream);
  lru_convert_kernel<<<3124, 256, 0, stream>>>(Wemb, Bre, Bim, Cre, Cim, Wcls,
                                               Wt, Bws, Cws, Wcl);
  lru_fused_kernel<<<1024, 256, 0, stream>>>(x, ln0g, ln0b, Wt, bemb, Bws, Cws,
                                             lng, lnb, nulog, thlog, gmlog,
                                             dskip, Wcl, bcls, carr, flags, out);
}

// Round 7
// 2031.434 us; speedup vs baseline: 1.1263x; 1.1263x over previous
//
#include <hip/hip_runtime.h>

typedef float f32x4 __attribute__((ext_vector_type(4)));
typedef __bf16 bf16x8 __attribute__((ext_vector_type(8)));

#define NSTAGE 20
#define TSEQ   2048
#define NST    128
#define NP2    256
#define NCLS   202

static __device__ __forceinline__ unsigned short f2b(float f) {
  return __builtin_bit_cast(unsigned short, (__bf16)f);
}

// ---------------------------------------------------------------------------
// Kernel 1: convert weights to bf16 in ws, with MFMA-friendly layouts.
//  Wt   [64][2048]  = W_embed^T
//  Bws  [20][256][64]: row n'=2n+p holds B_{re/im}[s][n][k] along k
//  Cws  [20][64][256]: row d holds (C_re[s][d][n], -C_im[s][d][n]) interleaved
//  Wclst[208][64]   = W_cls^T, rows >=202 zero
// ---------------------------------------------------------------------------
__global__ void lru_convert_kernel(const float* __restrict__ Wemb,
                                   const float* __restrict__ Bre, const float* __restrict__ Bim,
                                   const float* __restrict__ Cre, const float* __restrict__ Cim,
                                   const float* __restrict__ Wcls,
                                   unsigned short* __restrict__ Wt,
                                   unsigned short* __restrict__ Bws,
                                   unsigned short* __restrict__ Cws,
                                   unsigned short* __restrict__ Wclst)
{
  const int NWT = 64 * 2048;          // 131072
  const int NB  = NSTAGE * NP2 * 64;  // 327680
  const int NC  = NSTAGE * 64 * NP2;  // 327680
  const int NWC = 208 * 64;           // 13312
  int idx = blockIdx.x * 256 + threadIdx.x;
  if (idx < NWT) {
    int d = idx >> 11, k = idx & 2047;
    Wt[idx] = f2b(Wemb[k * 64 + d]);
  } else if (idx < NWT + NB) {
    int r = idx - NWT;
    int s = r / (NP2 * 64); int r2 = r % (NP2 * 64);
    int np = r2 >> 6, k = r2 & 63;
    int n = np >> 1, p = np & 1;
    float v = p ? Bim[(s * NST + n) * 64 + k] : Bre[(s * NST + n) * 64 + k];
    Bws[r] = f2b(v);
  } else if (idx < NWT + NB + NC) {
    int r = idx - NWT - NB;
    int s = r / (64 * NP2); int r2 = r % (64 * NP2);
    int d = r2 >> 8, np = r2 & 255;
    int n = np >> 1, p = np & 1;
    float v = p ? -Cim[(s * 64 + d) * NST + n] : Cre[(s * 64 + d) * NST + n];
    Cws[r] = f2b(v);
  } else if (idx < NWT + NB + NC + NWC) {
    int r = idx - NWT - NB - NC;
    int cls = r >> 6, k = r & 63;
    Wclst[r] = (cls < NCLS) ? f2b(Wcls[k * NCLS + cls]) : (unsigned short)0;
  }
}

// ---------------------------------------------------------------------------
// Fused persistent kernel (plain launch). Block (b,c) owns tokens
// [c*16, c*16+16) of batch b; h lives in LDS for the whole network.
// Carry handoff = Round-3-verified fence protocol (release fence -> flag
// atomic store; acquire fence before payload reads), but the reader polls
// in ROUNDS: relaxed flag loads + LDS counter, with a 3-barrier structure
// (reset -> B1 -> add -> B2 -> read -> B3) so the round-k read can never
// race the round-(k+1) reset. One acquire fence per FAILED round (instead
// of per poll iteration) kills Round 3's L2-invalidate storm.
// Dependencies point strictly to lower blockIdx -> deadlock-free.
// ---------------------------------------------------------------------------
__launch_bounds__(256)
__global__ void lru_fused_kernel(
    const float* __restrict__ x,
    const float* __restrict__ ln0g, const float* __restrict__ ln0b,
    const unsigned short* __restrict__ Wt, const float* __restrict__ bemb,
    const unsigned short* __restrict__ Bws, const unsigned short* __restrict__ Cws,
    const float* __restrict__ lng, const float* __restrict__ lnb,
    const float* __restrict__ nulog, const float* __restrict__ thlog,
    const float* __restrict__ gmlog, const float* __restrict__ dskip,
    const unsigned short* __restrict__ Wclst, const float* __restrict__ bcls,
    float* __restrict__ carr, unsigned* __restrict__ flags,
    float* __restrict__ out)
{
  __shared__ float hsm[16][68];
  __shared__ float zsm[16][68];
  __shared__ __align__(16) unsigned short zb[16][72];
  __shared__ __align__(16) float ucat[16][264];
  __shared__ __align__(16) unsigned short hcb[16][264];
  __shared__ float mu_s[16], rs_s[16];
  __shared__ int nmiss;

  const int tid = threadIdx.x;
  const int b = blockIdx.x >> 7;
  const int c = blockIdx.x & 127;
  const int t0 = c * 16;
  const int w = tid >> 6, lane = tid & 63;
  const int cl = lane & 15, q = lane >> 4;
  const int tg = tid >> 4, g = tid & 15;

  // ---- Phase E0: LN0 statistics (wave w -> tokens 4w..4w+3) ----
  for (int i = 0; i < 4; ++i) {
    int t = w * 4 + i;
    const float* xp = x + ((size_t)(b * TSEQ + t0 + t)) * 2048;
    float sum = 0.f, sq = 0.f;
    #pragma unroll
    for (int j = 0; j < 32; ++j) {
      float v = xp[lane + 64 * j];
      sum += v; sq += v * v;
    }
    #pragma unroll
    for (int m = 1; m < 64; m <<= 1) {
      sum += __shfl_xor(sum, m); sq += __shfl_xor(sq, m);
    }
    if (lane == 0) {
      float mu = sum * (1.f / 2048.f);
      float var = sq * (1.f / 2048.f) - mu * mu;
      mu_s[t] = mu;
      rs_s[t] = rsqrtf(var + 1e-5f);
    }
  }
  __syncthreads();

  // ---- Phase E1: embed GEMM (16 tok x 2048 @ 2048 x 64) -> hsm ----
  {
    const int st = tg;
    const int g4 = g * 4;
    const float muT = mu_s[st], rsT = rs_s[st];
    f32x4 acc = {0.f, 0.f, 0.f, 0.f};
    for (int kc = 0; kc < 32; ++kc) {
      __syncthreads();
      {
        const float* xp = x + ((size_t)(b * TSEQ + t0 + st)) * 2048 + kc * 64 + g4;
        float4 xv = *(const float4*)xp;
        float4 gv = *(const float4*)&ln0g[kc * 64 + g4];
        float4 bv = *(const float4*)&ln0b[kc * 64 + g4];
        float z0 = (xv.x - muT) * rsT * gv.x + bv.x;
        float z1 = (xv.y - muT) * rsT * gv.y + bv.y;
        float z2 = (xv.z - muT) * rsT * gv.z + bv.z;
        float z3 = (xv.w - muT) * rsT * gv.w + bv.w;
        *(unsigned*)&zb[st][g4]     = (unsigned)f2b(z0) | ((unsigned)f2b(z1) << 16);
        *(unsigned*)&zb[st][g4 + 2] = (unsigned)f2b(z2) | ((unsigned)f2b(z3) << 16);
      }
      __syncthreads();
      bf16x8 a0 = *(const bf16x8*)((const char*)&zb[0][0] + cl * 144 + q * 16);
      bf16x8 a1 = *(const bf16x8*)((const char*)&zb[0][0] + cl * 144 + 64 + q * 16);
      const unsigned short* wp = Wt + ((size_t)(w * 16 + cl)) * 2048 + kc * 64 + q * 8;
      bf16x8 w0 = *(const bf16x8*)wp;
      bf16x8 w1 = *(const bf16x8*)(wp + 32);
      acc = __builtin_amdgcn_mfma_f32_16x16x32_bf16(a0, w0, acc, 0, 0, 0);
      acc = __builtin_amdgcn_mfma_f32_16x16x32_bf16(a1, w1, acc, 0, 0, 0);
    }
    int d = w * 16 + cl;
    float be = bemb[d];
    #pragma unroll
    for (int r = 0; r < 4; ++r) hsm[q * 4 + r][d] = acc[r] + be;
  }
  __syncthreads();

  // ---- Stage loop ----
  for (int s = 0; s < NSTAGE; ++s) {
    float* carr_s = carr + ((size_t)(s * 8 + b)) * 128 * 256;
    unsigned* flag_s = flags + (size_t)(s * 8 + b) * 128;

    // LayerNorm over D=64 from hsm (16-lane subgroup per token)
    {
      float4 hv = *(const float4*)&hsm[tg][g * 4];
      float sum = hv.x + hv.y + hv.z + hv.w;
      sum += __shfl_xor(sum, 1); sum += __shfl_xor(sum, 2);
      sum += __shfl_xor(sum, 4); sum += __shfl_xor(sum, 8);
      float mu = sum * (1.f / 64.f);
      float d0 = hv.x - mu, d1 = hv.y - mu, d2 = hv.z - mu, d3 = hv.w - mu;
      float sq = d0 * d0 + d1 * d1 + d2 * d2 + d3 * d3;
      sq += __shfl_xor(sq, 1); sq += __shfl_xor(sq, 2);
      sq += __shfl_xor(sq, 4); sq += __shfl_xor(sq, 8);
      float rs = rsqrtf(sq * (1.f / 64.f) + 1e-5f);
      float4 gv = *(const float4*)&lng[s * 64 + g * 4];
      float4 bv = *(const float4*)&lnb[s * 64 + g * 4];
      float z0 = d0 * rs * gv.x + bv.x;
      float z1 = d1 * rs * gv.y + bv.y;
      float z2 = d2 * rs * gv.z + bv.z;
      float z3 = d3 * rs * gv.w + bv.w;
      zsm[tg][g * 4 + 0] = z0; zsm[tg][g * 4 + 1] = z1;
      zsm[tg][g * 4 + 2] = z2; zsm[tg][g * 4 + 3] = z3;
      *(unsigned*)&zb[tg][g * 4]     = (unsigned)f2b(z0) | ((unsigned)f2b(z1) << 16);
      *(unsigned*)&zb[tg][g * 4 + 2] = (unsigned)f2b(z2) | ((unsigned)f2b(z3) << 16);
    }
    __syncthreads();

    // U = Z * B^T scaled by gamma (MFMA)
    {
      bf16x8 a0 = *(const bf16x8*)((const char*)&zb[0][0] + cl * 144 + q * 16);
      bf16x8 a1 = *(const bf16x8*)((const char*)&zb[0][0] + cl * 144 + 64 + q * 16);
      const unsigned short* bb = Bws + (size_t)s * NP2 * 64;
      #pragma unroll
      for (int ti = 0; ti < 4; ++ti) {
        int np0 = (w * 4 + ti) * 16;
        const unsigned short* bp = bb + (np0 + cl) * 64 + q * 8;
        bf16x8 b0 = *(const bf16x8*)bp;
        bf16x8 b1 = *(const bf16x8*)(bp + 32);
        f32x4 acc = {0.f, 0.f, 0.f, 0.f};
        acc = __builtin_amdgcn_mfma_f32_16x16x32_bf16(a0, b0, acc, 0, 0, 0);
        acc = __builtin_amdgcn_mfma_f32_16x16x32_bf16(a1, b1, acc, 0, 0, 0);
        int np = np0 + cl;
        float gam = __expf(gmlog[s * NST + (np >> 1)]);
        ucat[q * 4 + 0][np] = acc[0] * gam;
        ucat[q * 4 + 1][np] = acc[1] * gam;
        ucat[q * 4 + 2][np] = acc[2] * gam;
        ucat[q * 4 + 3][np] = acc[3] * gam;
      }
    }
    __syncthreads();

    // local 16-step scan (in place) + plain payload store
    float lamr = 0.f, lami = 0.f, ar = 0.f, ai = 0.f;
    if (tid < NST) {
      int n = tid;
      float mag = __expf(-__expf(nulog[s * NST + n]));
      float th  = __expf(thlog[s * NST + n]);
      lamr = mag * __cosf(th);
      lami = mag * __sinf(th);
      float hr = 0.f, hi = 0.f;
      #pragma unroll
      for (int t = 0; t < 16; ++t) {
        float ur = ucat[t][2 * n], ui = ucat[t][2 * n + 1];
        float nr = fmaf(lamr, hr, fmaf(-lami, hi, ur));
        float ni = fmaf(lamr, hi, fmaf(lami, hr, ui));
        hr = nr; hi = ni;
        ucat[t][2 * n] = hr; ucat[t][2 * n + 1] = hi;
      }
      float* cw = carr_s + (size_t)c * 256 + 2 * n;
      cw[0] = hr;
      cw[1] = hi;
      // lam^16
      ar = lamr; ai = lami;
      #pragma unroll
      for (int it = 0; it < 4; ++it) {
        float nr = ar * ar - ai * ai;
        float ni = 2.f * ar * ai;
        ar = nr; ai = ni;
      }
    }
    __syncthreads();   // payload stores acked into L2

    // publish (Round-3-proven): release fence (wbl2) + agent atomic flag
    if (tid == 0) {
      __builtin_amdgcn_fence(__ATOMIC_RELEASE, "agent");
      __hip_atomic_store(&flag_s[c], 1u, __ATOMIC_RELEASE, __HIP_MEMORY_SCOPE_AGENT);
    }

    // wait for predecessors: 3-barrier round poll, one inv per failed round
    if (c > 0) {
      for (;;) {
        if (tid == 0) nmiss = 0;
        __syncthreads();                   // B1: reset visible before adds
        if (tid < c) {
          if (__hip_atomic_load(&flag_s[tid], __ATOMIC_RELAXED,
                                __HIP_MEMORY_SCOPE_AGENT) == 0u)
            atomicAdd(&nmiss, 1);
        }
        __syncthreads();                   // B2: adds complete before read
        int m = nmiss;
        __syncthreads();                   // B3: reads complete before next reset
        if (m == 0) break;                 // uniform decision
        __builtin_amdgcn_fence(__ATOMIC_ACQUIRE, "agent");  // inv stale flags
        __builtin_amdgcn_s_sleep(4);
      }
      __builtin_amdgcn_fence(__ATOMIC_ACQUIRE, "agent");    // payload visibility
    }

    // prefix over earlier chunks (plain loads, unrolled for MLP) + apply -> hcb
    if (tid < NST) {
      int n = tid;
      float Pr = 0.f, Pi = 0.f;
      const float* cb = carr_s + 2 * n;
      #pragma unroll 4
      for (int j = 0; j < c; ++j) {
        float cr = cb[j * 256];
        float ci = cb[j * 256 + 1];
        float nr = fmaf(ar, Pr, fmaf(-ai, Pi, cr));
        float ni = fmaf(ar, Pi, fmaf(ai, Pr, ci));
        Pr = nr; Pi = ni;
      }
      float mr = lamr, mi = lami;
      #pragma unroll
      for (int t = 0; t < 16; ++t) {
        float hgr = ucat[t][2 * n]     + mr * Pr - mi * Pi;
        float hgi = ucat[t][2 * n + 1] + mr * Pi + mi * Pr;
        *(unsigned*)&hcb[t][2 * n] = (unsigned)f2b(hgr) | ((unsigned)f2b(hgi) << 16);
        float nmr = mr * lamr - mi * lami;
        float nmi = mr * lami + mi * lamr;
        mr = nmr; mi = nmi;
      }
    }
    __syncthreads();

    // Y = Hcat * Cc (MFMA, K=256); h += y + Dskip*z  (in LDS)
    {
      int d0 = w * 16;
      const unsigned short* cp = Cws + ((size_t)s * 64 + d0 + cl) * NP2 + q * 8;
      f32x4 acc = {0.f, 0.f, 0.f, 0.f};
      #pragma unroll
      for (int ks = 0; ks < 8; ++ks) {
        bf16x8 a  = *(const bf16x8*)((const char*)&hcb[0][0] + cl * 528 + ks * 64 + q * 16);
        bf16x8 cc = *(const bf16x8*)(cp + ks * 32);
        acc = __builtin_amdgcn_mfma_f32_16x16x32_bf16(a, cc, acc, 0, 0, 0);
      }
      int d = d0 + cl;
      float dk = dskip[s * 64 + d];
      #pragma unroll
      for (int r = 0; r < 4; ++r) {
        int t = q * 4 + r;
        hsm[t][d] = hsm[t][d] + acc[r] + dk * zsm[t][d];
      }
    }
    __syncthreads();
  }

  // ---- Classifier: out = h @ W_cls + b_cls ----
  {
    *(unsigned*)&zb[tg][g * 4] =
        (unsigned)f2b(hsm[tg][g * 4 + 0]) | ((unsigned)f2b(hsm[tg][g * 4 + 1]) << 16);
    *(unsigned*)&zb[tg][g * 4 + 2] =
        (unsigned)f2b(hsm[tg][g * 4 + 2]) | ((unsigned)f2b(hsm[tg][g * 4 + 3]) << 16);
  }
  __syncthreads();
  {
    bf16x8 a0 = *(const bf16x8*)((const char*)&zb[0][0] + cl * 144 + q * 16);
    bf16x8 a1 = *(const bf16x8*)((const char*)&zb[0][0] + cl * 144 + 64 + q * 16);
    for (int ti = w; ti < 13; ti += 4) {
      int cls0 = ti * 16;
      const unsigned short* wp = Wclst + (cls0 + cl) * 64 + q * 8;
      bf16x8 b0 = *(const bf16x8*)wp;
      bf16x8 b1 = *(const bf16x8*)(wp + 32);
      f32x4 acc = {0.f, 0.f, 0.f, 0.f};
      acc = __builtin_amdgcn_mfma_f32_16x16x32_bf16(a0, b0, acc, 0, 0, 0);
      acc = __builtin_amdgcn_mfma_f32_16x16x32_bf16(a1, b1, acc, 0, 0, 0);
      int cls = cls0 + cl;
      if (cls < NCLS) {
        float bc = bcls[cls];
        #pragma unroll
        for (int r = 0; r < 4; ++r) {
          int t = q * 4 + r;
          out[((size_t)(b * TSEQ + t0 + t)) * NCLS + cls] = acc[r] + bc;
        }
      }
    }
  }
}

// ---------------------------------------------------------------------------
extern "C" void kernel_launch(void* const* d_in, const int* in_sizes, int n_in,
                              void* d_out, int out_size, void* d_ws, size_t ws_size,
                              hipStream_t stream) {
  (void)in_sizes; (void)n_in; (void)out_size; (void)ws_size;
  const float* x     = (const float*)d_in[0];
  const float* ln0g  = (const float*)d_in[1];
  const float* ln0b  = (const float*)d_in[2];
  const float* Wemb  = (const float*)d_in[3];
  const float* bemb  = (const float*)d_in[4];
  const float* lng   = (const float*)d_in[5];
  const float* lnb   = (const float*)d_in[6];
  const float* nulog = (const float*)d_in[7];
  const float* thlog = (const float*)d_in[8];
  const float* gmlog = (const float*)d_in[9];
  const float* Bre   = (const float*)d_in[10];
  const float* Bim   = (const float*)d_in[11];
  const float* Cre   = (const float*)d_in[12];
  const float* Cim   = (const float*)d_in[13];
  const float* dskip = (const float*)d_in[14];
  const float* Wcls  = (const float*)d_in[15];
  const float* bcls  = (const float*)d_in[16];
  float* out = (float*)d_out;

  char* ws = (char*)d_ws;
  // ws layout (bytes):
  //  carr  @0        : 20*8*128*256*4 = 20971520   (per-stage carries)
  //  flags @20971520 : 20*8*128*4     = 81920
  //  Bws   @21053440 : 20*256*64*2    = 655360
  //  Cws   @21708800 : 655360
  //  Wt    @22364160 : 64*2048*2     = 262144
  //  Wclst @22626304 : 208*64*2      = 26624      (end 22652928)
  float* carr          = (float*)(ws + 0);
  unsigned* flags      = (unsigned*)(ws + 20971520);
  unsigned short* Bws  = (unsigned short*)(ws + 21053440);
  unsigned short* Cws  = (unsigned short*)(ws + 21708800);
  unsigned short* Wt   = (unsigned short*)(ws + 22364160);
  unsigned short* Wcl  = (unsigned short*)(ws + 22626304);

  (void)hipMemsetAsync(flags, 0, 20 * 8 * 128 * sizeof(unsigned), stream);
  lru_convert_kernel<<<3124, 256, 0, stream>>>(Wemb, Bre, Bim, Cre, Cim, Wcls,
                                               Wt, Bws, Cws, Wcl);
  lru_fused_kernel<<<1024, 256, 0, stream>>>(x, ln0g, ln0b, Wt, bemb, Bws, Cws,
                                             lng, lnb, nulog, thlog, gmlog,
                                             dskip, Wcl, bcls, carr, flags, out);
}

// Round 8
// 661.192 us; speedup vs baseline: 3.4603x; 3.0724x over previous
//
#include <hip/hip_runtime.h>

typedef float f32x4 __attribute__((ext_vector_type(4)));
typedef __bf16 bf16x8 __attribute__((ext_vector_type(8)));

#define NSTAGE 20
#define TSEQ   2048
#define NST    128
#define NP2    256
#define NCLS   202
#define NCHUNK 32          // 64-token chunks per sequence
#define CHTOK  64

static __device__ __forceinline__ unsigned short f2b(float f) {
  return __builtin_bit_cast(unsigned short, (__bf16)f);
}

// ---------------------------------------------------------------------------
// Kernel 1: convert weights to bf16 in ws (R0-verbatim, verified).
//  Wt   [64][2048]  = W_embed^T
//  Bws  [20][256][64]: row n'=2n+p holds B_{re/im}[s][n][k] along k
//  Cws  [20][64][256]: row d holds (C_re[s][d][n], -C_im[s][d][n]) interleaved
//  Wclst[208][64]   = W_cls^T, rows >=202 zero
// ---------------------------------------------------------------------------
__global__ void lru_convert_kernel(const float* __restrict__ Wemb,
                                   const float* __restrict__ Bre, const float* __restrict__ Bim,
                                   const float* __restrict__ Cre, const float* __restrict__ Cim,
                                   const float* __restrict__ Wcls,
                                   unsigned short* __restrict__ Wt,
                                   unsigned short* __restrict__ Bws,
                                   unsigned short* __restrict__ Cws,
                                   unsigned short* __restrict__ Wclst)
{
  const int NWT = 64 * 2048;
  const int NB  = NSTAGE * NP2 * 64;
  const int NC  = NSTAGE * 64 * NP2;
  const int NWC = 208 * 64;
  int idx = blockIdx.x * 256 + threadIdx.x;
  if (idx < NWT) {
    int d = idx >> 11, k = idx & 2047;
    Wt[idx] = f2b(Wemb[k * 64 + d]);
  } else if (idx < NWT + NB) {
    int r = idx - NWT;
    int s = r / (NP2 * 64); int r2 = r % (NP2 * 64);
    int np = r2 >> 6, k = r2 & 63;
    int n = np >> 1, p = np & 1;
    float v = p ? Bim[(s * NST + n) * 64 + k] : Bre[(s * NST + n) * 64 + k];
    Bws[r] = f2b(v);
  } else if (idx < NWT + NB + NC) {
    int r = idx - NWT - NB;
    int s = r / (64 * NP2); int r2 = r % (64 * NP2);
    int d = r2 >> 8, np = r2 & 255;
    int n = np >> 1, p = np & 1;
    float v = p ? -Cim[(s * 64 + d) * NST + n] : Cre[(s * 64 + d) * NST + n];
    Cws[r] = f2b(v);
  } else if (idx < NWT + NB + NC + NWC) {
    int r = idx - NWT - NB - NC;
    int cls = r >> 6, k = r & 63;
    Wclst[r] = (cls < NCLS) ? f2b(Wcls[k * NCLS + cls]) : (unsigned short)0;
  }
}

// ---------------------------------------------------------------------------
// Kernel 2: LN0 + embed GEMM, 1024 blocks x 256 threads, 16-token tiles.
// (R7-verified E0/E1 fragments; writes h0 to global.)
// ---------------------------------------------------------------------------
__launch_bounds__(256)
__global__ void lru_embed_kernel(const float* __restrict__ x,
                                 const float* __restrict__ g0,
                                 const float* __restrict__ b0,
                                 const unsigned short* __restrict__ Wt,
                                 const float* __restrict__ bemb,
                                 float* __restrict__ h0)
{
  __shared__ __align__(16) unsigned short zb[16][72];
  __shared__ float mu_s[16], rs_s[16];

  const int tid = threadIdx.x;
  const int b  = blockIdx.x >> 7;
  const int t0 = (blockIdx.x & 127) * 16;
  const int w = tid >> 6, lane = tid & 63;
  const int cl = lane & 15, q = lane >> 4;
  const int tg = tid >> 4, g = tid & 15;

  // LN0 statistics: wave w -> tokens 4w..4w+3
  for (int i = 0; i < 4; ++i) {
    int t = w * 4 + i;
    const float* xp = x + ((size_t)(b * TSEQ + t0 + t)) * 2048;
    float sum = 0.f, sq = 0.f;
    #pragma unroll
    for (int j = 0; j < 32; ++j) {
      float v = xp[lane + 64 * j];
      sum += v; sq += v * v;
    }
    #pragma unroll
    for (int m = 1; m < 64; m <<= 1) {
      sum += __shfl_xor(sum, m); sq += __shfl_xor(sq, m);
    }
    if (lane == 0) {
      float mu = sum * (1.f / 2048.f);
      float var = sq * (1.f / 2048.f) - mu * mu;
      mu_s[t] = mu;
      rs_s[t] = rsqrtf(var + 1e-5f);
    }
  }
  __syncthreads();

  {
    const int g4 = g * 4;
    const float muT = mu_s[tg], rsT = rs_s[tg];
    f32x4 acc = {0.f, 0.f, 0.f, 0.f};
    for (int kc = 0; kc < 32; ++kc) {
      __syncthreads();
      {
        const float* xp = x + ((size_t)(b * TSEQ + t0 + tg)) * 2048 + kc * 64 + g4;
        float4 xv = *(const float4*)xp;
        float4 gv = *(const float4*)&g0[kc * 64 + g4];
        float4 bv = *(const float4*)&b0[kc * 64 + g4];
        float z0 = (xv.x - muT) * rsT * gv.x + bv.x;
        float z1 = (xv.y - muT) * rsT * gv.y + bv.y;
        float z2 = (xv.z - muT) * rsT * gv.z + bv.z;
        float z3 = (xv.w - muT) * rsT * gv.w + bv.w;
        *(unsigned*)&zb[tg][g4]     = (unsigned)f2b(z0) | ((unsigned)f2b(z1) << 16);
        *(unsigned*)&zb[tg][g4 + 2] = (unsigned)f2b(z2) | ((unsigned)f2b(z3) << 16);
      }
      __syncthreads();
      bf16x8 a0 = *(const bf16x8*)((const char*)&zb[0][0] + cl * 144 + q * 16);
      bf16x8 a1 = *(const bf16x8*)((const char*)&zb[0][0] + cl * 144 + 64 + q * 16);
      const unsigned short* wp = Wt + ((size_t)(w * 16 + cl)) * 2048 + kc * 64 + q * 8;
      bf16x8 w0 = *(const bf16x8*)wp;
      bf16x8 w1 = *(const bf16x8*)(wp + 32);
      acc = __builtin_amdgcn_mfma_f32_16x16x32_bf16(a0, w0, acc, 0, 0, 0);
      acc = __builtin_amdgcn_mfma_f32_16x16x32_bf16(a1, w1, acc, 0, 0, 0);
    }
    int d = w * 16 + cl;
    float be = bemb[d];
    #pragma unroll
    for (int r = 0; r < 4; ++r)
      h0[((size_t)(b * TSEQ + t0 + q * 4 + r)) * 64 + d] = acc[r] + be;
  }
}

// ---------------------------------------------------------------------------
// Kernel 3: stage-0 carry. Block (b,c) owns 64 tokens (4 x 16-token
// sub-tiles, scan state carried in registers across sub-tiles).
// ---------------------------------------------------------------------------
__launch_bounds__(256)
__global__ void lru_carry0_kernel(const float* __restrict__ h0,
                                  const unsigned short* __restrict__ Bws,
                                  const float* __restrict__ lng,
                                  const float* __restrict__ lnb,
                                  const float* __restrict__ nulog,
                                  const float* __restrict__ thlog,
                                  const float* __restrict__ gmlog,
                                  float* __restrict__ carr)
{
  __shared__ __align__(16) unsigned short zb[16][72];
  __shared__ __align__(16) float ucat[16][264];

  const int tid = threadIdx.x;
  const int b = blockIdx.x >> 5;
  const int c = blockIdx.x & 31;
  const int t0 = c * CHTOK;
  const int w = tid >> 6, lane = tid & 63;
  const int cl = lane & 15, q = lane >> 4;
  const int tg = tid >> 4, g = tid & 15;

  float lamr = 0.f, lami = 0.f, hr = 0.f, hi = 0.f;
  if (tid < NST) {
    float mag = __expf(-__expf(nulog[tid]));
    float th  = __expf(thlog[tid]);
    lamr = mag * __cosf(th);
    lami = mag * __sinf(th);
  }

  for (int sb = 0; sb < 4; ++sb) {
    int tb = t0 + sb * 16;
    __syncthreads();     // protect zb/ucat reuse across sub-tiles
    {
      float4 hv = *(const float4*)&h0[((size_t)(b * TSEQ + tb + tg)) * 64 + g * 4];
      float sum = hv.x + hv.y + hv.z + hv.w;
      sum += __shfl_xor(sum, 1); sum += __shfl_xor(sum, 2);
      sum += __shfl_xor(sum, 4); sum += __shfl_xor(sum, 8);
      float mu = sum * (1.f / 64.f);
      float d0 = hv.x - mu, d1 = hv.y - mu, d2 = hv.z - mu, d3 = hv.w - mu;
      float sq = d0 * d0 + d1 * d1 + d2 * d2 + d3 * d3;
      sq += __shfl_xor(sq, 1); sq += __shfl_xor(sq, 2);
      sq += __shfl_xor(sq, 4); sq += __shfl_xor(sq, 8);
      float rs = rsqrtf(sq * (1.f / 64.f) + 1e-5f);
      float4 gv = *(const float4*)&lng[g * 4];
      float4 bv = *(const float4*)&lnb[g * 4];
      float z0 = d0 * rs * gv.x + bv.x;
      float z1 = d1 * rs * gv.y + bv.y;
      float z2 = d2 * rs * gv.z + bv.z;
      float z3 = d3 * rs * gv.w + bv.w;
      *(unsigned*)&zb[tg][g * 4]     = (unsigned)f2b(z0) | ((unsigned)f2b(z1) << 16);
      *(unsigned*)&zb[tg][g * 4 + 2] = (unsigned)f2b(z2) | ((unsigned)f2b(z3) << 16);
    }
    __syncthreads();
    {
      bf16x8 a0 = *(const bf16x8*)((const char*)&zb[0][0] + cl * 144 + q * 16);
      bf16x8 a1 = *(const bf16x8*)((const char*)&zb[0][0] + cl * 144 + 64 + q * 16);
      #pragma unroll
      for (int ti = 0; ti < 4; ++ti) {
        int np0 = (w * 4 + ti) * 16;
        const unsigned short* bp = Bws + (np0 + cl) * 64 + q * 8;
        bf16x8 b0 = *(const bf16x8*)bp;
        bf16x8 b1 = *(const bf16x8*)(bp + 32);
        f32x4 acc = {0.f, 0.f, 0.f, 0.f};
        acc = __builtin_amdgcn_mfma_f32_16x16x32_bf16(a0, b0, acc, 0, 0, 0);
        acc = __builtin_amdgcn_mfma_f32_16x16x32_bf16(a1, b1, acc, 0, 0, 0);
        int np = np0 + cl;
        float gam = __expf(gmlog[np >> 1]);
        ucat[q * 4 + 0][np] = acc[0] * gam;
        ucat[q * 4 + 1][np] = acc[1] * gam;
        ucat[q * 4 + 2][np] = acc[2] * gam;
        ucat[q * 4 + 3][np] = acc[3] * gam;
      }
    }
    __syncthreads();
    if (tid < NST) {
      int n = tid;
      #pragma unroll
      for (int t = 0; t < 16; ++t) {
        float ur = ucat[t][2 * n], ui = ucat[t][2 * n + 1];
        float nr = fmaf(lamr, hr, fmaf(-lami, hi, ur));
        float ni = fmaf(lamr, hi, fmaf(lami, hr, ui));
        hr = nr; hi = ni;
      }
    }
  }
  if (tid < NST) {
    float* cw = carr + ((size_t)(b * NCHUNK + c)) * 256 + 2 * tid;
    cw[0] = hr;
    cw[1] = hi;
  }
}

// ---------------------------------------------------------------------------
// Kernel 4: apply stage s + carry stage s+1 (one dispatch per stage).
// Block (b,c) owns 64 tokens. Pass 1: prefix P from carrin (dispatch-boundary
// coherent), seeded scan, C-proj, h update into LDS. Pass 2: LN+B-proj+scan
// of the UPDATED h -> carrout for stage s+1; write h back to global.
// Last stage: classifier instead of pass 2.
// ---------------------------------------------------------------------------
__launch_bounds__(256)
__global__ void lru_applycarry_kernel(float* __restrict__ h0,
                                      const float* __restrict__ carrin,
                                      float* __restrict__ carrout,
                                      const unsigned short* __restrict__ Bws,
                                      const unsigned short* __restrict__ Cws,
                                      const float* __restrict__ lng,
                                      const float* __restrict__ lnb,
                                      const float* __restrict__ nulog,
                                      const float* __restrict__ thlog,
                                      const float* __restrict__ gmlog,
                                      const float* __restrict__ dskip,
                                      int s, int last,
                                      const unsigned short* __restrict__ Wclst,
                                      const float* __restrict__ bcls,
                                      float* __restrict__ out)
{
  __shared__ float hsm64[64][68];
  __shared__ float hs[16][68];
  __shared__ float zsm[16][68];
  __shared__ __align__(16) unsigned short zb[16][72];
  __shared__ __align__(16) float ucat[16][264];
  __shared__ __align__(16) unsigned short hcb[16][264];

  const int tid = threadIdx.x;
  const int b = blockIdx.x >> 5;
  const int c = blockIdx.x & 31;
  const int t0 = c * CHTOK;
  const int w = tid >> 6, lane = tid & 63;
  const int cl = lane & 15, q = lane >> 4;
  const int tg = tid >> 4, g = tid & 15;

  // lambda for stage s, lam^64, prefix P over earlier chunks
  float lamr = 0.f, lami = 0.f, Pr = 0.f, Pi = 0.f;
  if (tid < NST) {
    int n = tid;
    float mag = __expf(-__expf(nulog[s * NST + n]));
    float th  = __expf(thlog[s * NST + n]);
    lamr = mag * __cosf(th);
    lami = mag * __sinf(th);
    float ar = lamr, ai = lami;
    #pragma unroll
    for (int it = 0; it < 6; ++it) {       // lam^64
      float nr = ar * ar - ai * ai;
      float ni = 2.f * ar * ai;
      ar = nr; ai = ni;
    }
    const float* cb = carrin + (size_t)b * NCHUNK * 256 + 2 * n;
    #pragma unroll 4
    for (int j = 0; j < c; ++j) {
      float cr = cb[j * 256];
      float ci = cb[j * 256 + 1];
      float nr = fmaf(ar, Pr, fmaf(-ai, Pi, cr));
      float ni = fmaf(ar, Pi, fmaf(ai, Pr, ci));
      Pr = nr; Pi = ni;
    }
  }

  // ---- pass 1: apply stage s (seeded scan) ----
  float hr = Pr, hi = Pi;
  for (int sb = 0; sb < 4; ++sb) {
    int tb = t0 + sb * 16;
    __syncthreads();   // protect LDS reuse across sub-tiles
    {
      float4 hv = *(const float4*)&h0[((size_t)(b * TSEQ + tb + tg)) * 64 + g * 4];
      hs[tg][g * 4 + 0] = hv.x; hs[tg][g * 4 + 1] = hv.y;
      hs[tg][g * 4 + 2] = hv.z; hs[tg][g * 4 + 3] = hv.w;
      float sum = hv.x + hv.y + hv.z + hv.w;
      sum += __shfl_xor(sum, 1); sum += __shfl_xor(sum, 2);
      sum += __shfl_xor(sum, 4); sum += __shfl_xor(sum, 8);
      float mu = sum * (1.f / 64.f);
      float d0 = hv.x - mu, d1 = hv.y - mu, d2 = hv.z - mu, d3 = hv.w - mu;
      float sq = d0 * d0 + d1 * d1 + d2 * d2 + d3 * d3;
      sq += __shfl_xor(sq, 1); sq += __shfl_xor(sq, 2);
      sq += __shfl_xor(sq, 4); sq += __shfl_xor(sq, 8);
      float rs = rsqrtf(sq * (1.f / 64.f) + 1e-5f);
      float4 gv = *(const float4*)&lng[s * 64 + g * 4];
      float4 bv = *(const float4*)&lnb[s * 64 + g * 4];
      float z0 = d0 * rs * gv.x + bv.x;
      float z1 = d1 * rs * gv.y + bv.y;
      float z2 = d2 * rs * gv.z + bv.z;
      float z3 = d3 * rs * gv.w + bv.w;
      zsm[tg][g * 4 + 0] = z0; zsm[tg][g * 4 + 1] = z1;
      zsm[tg][g * 4 + 2] = z2; zsm[tg][g * 4 + 3] = z3;
      *(unsigned*)&zb[tg][g * 4]     = (unsigned)f2b(z0) | ((unsigned)f2b(z1) << 16);
      *(unsigned*)&zb[tg][g * 4 + 2] = (unsigned)f2b(z2) | ((unsigned)f2b(z3) << 16);
    }
    __syncthreads();
    {
      bf16x8 a0 = *(const bf16x8*)((const char*)&zb[0][0] + cl * 144 + q * 16);
      bf16x8 a1 = *(const bf16x8*)((const char*)&zb[0][0] + cl * 144 + 64 + q * 16);
      const unsigned short* bb = Bws + (size_t)s * NP2 * 64;
      #pragma unroll
      for (int ti = 0; ti < 4; ++ti) {
        int np0 = (w * 4 + ti) * 16;
        const unsigned short* bp = bb + (np0 + cl) * 64 + q * 8;
        bf16x8 b0 = *(const bf16x8*)bp;
        bf16x8 b1 = *(const bf16x8*)(bp + 32);
        f32x4 acc = {0.f, 0.f, 0.f, 0.f};
        acc = __builtin_amdgcn_mfma_f32_16x16x32_bf16(a0, b0, acc, 0, 0, 0);
        acc = __builtin_amdgcn_mfma_f32_16x16x32_bf16(a1, b1, acc, 0, 0, 0);
        int np = np0 + cl;
        float gam = __expf(gmlog[s * NST + (np >> 1)]);
        ucat[q * 4 + 0][np] = acc[0] * gam;
        ucat[q * 4 + 1][np] = acc[1] * gam;
        ucat[q * 4 + 2][np] = acc[2] * gam;
        ucat[q * 4 + 3][np] = acc[3] * gam;
      }
    }
    __syncthreads();
    if (tid < NST) {
      int n = tid;
      #pragma unroll
      for (int t = 0; t < 16; ++t) {
        float ur = ucat[t][2 * n], ui = ucat[t][2 * n + 1];
        float nr = fmaf(lamr, hr, fmaf(-lami, hi, ur));
        float ni = fmaf(lamr, hi, fmaf(lami, hr, ui));
        hr = nr; hi = ni;
        *(unsigned*)&hcb[t][2 * n] = (unsigned)f2b(hr) | ((unsigned)f2b(hi) << 16);
      }
    }
    __syncthreads();
    {
      int d0 = w * 16;
      const unsigned short* cp = Cws + ((size_t)s * 64 + d0 + cl) * NP2 + q * 8;
      f32x4 acc = {0.f, 0.f, 0.f, 0.f};
      #pragma unroll
      for (int ks = 0; ks < 8; ++ks) {
        bf16x8 a  = *(const bf16x8*)((const char*)&hcb[0][0] + cl * 528 + ks * 64 + q * 16);
        bf16x8 cc = *(const bf16x8*)(cp + ks * 32);
        acc = __builtin_amdgcn_mfma_f32_16x16x32_bf16(a, cc, acc, 0, 0, 0);
      }
      int d = d0 + cl;
      float dk = dskip[s * 64 + d];
      #pragma unroll
      for (int r = 0; r < 4; ++r) {
        int t = q * 4 + r;
        hsm64[sb * 16 + t][d] = hs[t][d] + acc[r] + dk * zsm[t][d];
      }
    }
  }

  if (!last) {
    // ---- pass 2: carry for stage s+1 from updated h ----
    const int s1 = s + 1;
    float lam2r = 0.f, lam2i = 0.f, h2r = 0.f, h2i = 0.f;
    if (tid < NST) {
      float mag = __expf(-__expf(nulog[s1 * NST + tid]));
      float th  = __expf(thlog[s1 * NST + tid]);
      lam2r = mag * __cosf(th);
      lam2i = mag * __sinf(th);
    }
    for (int sb = 0; sb < 4; ++sb) {
      __syncthreads();
      {
        float4 hv = *(const float4*)&hsm64[sb * 16 + tg][g * 4];
        float sum = hv.x + hv.y + hv.z + hv.w;
        sum += __shfl_xor(sum, 1); sum += __shfl_xor(sum, 2);
        sum += __shfl_xor(sum, 4); sum += __shfl_xor(sum, 8);
        float mu = sum * (1.f / 64.f);
        float d0 = hv.x - mu, d1 = hv.y - mu, d2 = hv.z - mu, d3 = hv.w - mu;
        float sq = d0 * d0 + d1 * d1 + d2 * d2 + d3 * d3;
        sq += __shfl_xor(sq, 1); sq += __shfl_xor(sq, 2);
        sq += __shfl_xor(sq, 4); sq += __shfl_xor(sq, 8);
        float rs = rsqrtf(sq * (1.f / 64.f) + 1e-5f);
        float4 gv = *(const float4*)&lng[s1 * 64 + g * 4];
        float4 bv = *(const float4*)&lnb[s1 * 64 + g * 4];
        float z0 = d0 * rs * gv.x + bv.x;
        float z1 = d1 * rs * gv.y + bv.y;
        float z2 = d2 * rs * gv.z + bv.z;
        float z3 = d3 * rs * gv.w + bv.w;
        *(unsigned*)&zb[tg][g * 4]     = (unsigned)f2b(z0) | ((unsigned)f2b(z1) << 16);
        *(unsigned*)&zb[tg][g * 4 + 2] = (unsigned)f2b(z2) | ((unsigned)f2b(z3) << 16);
      }
      __syncthreads();
      {
        bf16x8 a0 = *(const bf16x8*)((const char*)&zb[0][0] + cl * 144 + q * 16);
        bf16x8 a1 = *(const bf16x8*)((const char*)&zb[0][0] + cl * 144 + 64 + q * 16);
        const unsigned short* bb = Bws + (size_t)s1 * NP2 * 64;
        #pragma unroll
        for (int ti = 0; ti < 4; ++ti) {
          int np0 = (w * 4 + ti) * 16;
          const unsigned short* bp = bb + (np0 + cl) * 64 + q * 8;
          bf16x8 b0 = *(const bf16x8*)bp;
          bf16x8 b1 = *(const bf16x8*)(bp + 32);
          f32x4 acc = {0.f, 0.f, 0.f, 0.f};
          acc = __builtin_amdgcn_mfma_f32_16x16x32_bf16(a0, b0, acc, 0, 0, 0);
          acc = __builtin_amdgcn_mfma_f32_16x16x32_bf16(a1, b1, acc, 0, 0, 0);
          int np = np0 + cl;
          float gam = __expf(gmlog[s1 * NST + (np >> 1)]);
          ucat[q * 4 + 0][np] = acc[0] * gam;
          ucat[q * 4 + 1][np] = acc[1] * gam;
          ucat[q * 4 + 2][np] = acc[2] * gam;
          ucat[q * 4 + 3][np] = acc[3] * gam;
        }
      }
      __syncthreads();
      if (tid < NST) {
        int n = tid;
        #pragma unroll
        for (int t = 0; t < 16; ++t) {
          float ur = ucat[t][2 * n], ui = ucat[t][2 * n + 1];
          float nr = fmaf(lam2r, h2r, fmaf(-lam2i, h2i, ur));
          float ni = fmaf(lam2r, h2i, fmaf(lam2i, h2r, ui));
          h2r = nr; h2i = ni;
        }
      }
    }
    if (tid < NST) {
      float* cw = carrout + ((size_t)(b * NCHUNK + c)) * 256 + 2 * tid;
      cw[0] = h2r;
      cw[1] = h2i;
    }
    // write updated h tile back (own tile only; no cross-block hazard)
    #pragma unroll
    for (int sb = 0; sb < 4; ++sb) {
      float4 hv;
      hv.x = hsm64[sb * 16 + tg][g * 4 + 0];
      hv.y = hsm64[sb * 16 + tg][g * 4 + 1];
      hv.z = hsm64[sb * 16 + tg][g * 4 + 2];
      hv.w = hsm64[sb * 16 + tg][g * 4 + 3];
      *(float4*)&h0[((size_t)(b * TSEQ + t0 + sb * 16 + tg)) * 64 + g * 4] = hv;
    }
  } else {
    // ---- classifier: out = h @ W_cls + b_cls ----
    for (int sb = 0; sb < 4; ++sb) {
      int tb = t0 + sb * 16;
      __syncthreads();
      {
        *(unsigned*)&zb[tg][g * 4] =
            (unsigned)f2b(hsm64[sb * 16 + tg][g * 4 + 0]) |
            ((unsigned)f2b(hsm64[sb * 16 + tg][g * 4 + 1]) << 16);
        *(unsigned*)&zb[tg][g * 4 + 2] =
            (unsigned)f2b(hsm64[sb * 16 + tg][g * 4 + 2]) |
            ((unsigned)f2b(hsm64[sb * 16 + tg][g * 4 + 3]) << 16);
      }
      __syncthreads();
      bf16x8 a0 = *(const bf16x8*)((const char*)&zb[0][0] + cl * 144 + q * 16);
      bf16x8 a1 = *(const bf16x8*)((const char*)&zb[0][0] + cl * 144 + 64 + q * 16);
      for (int ti = w; ti < 13; ti += 4) {
        int cls0 = ti * 16;
        const unsigned short* wp = Wclst + (cls0 + cl) * 64 + q * 8;
        bf16x8 b0 = *(const bf16x8*)wp;
        bf16x8 b1 = *(const bf16x8*)(wp + 32);
        f32x4 acc = {0.f, 0.f, 0.f, 0.f};
        acc = __builtin_amdgcn_mfma_f32_16x16x32_bf16(a0, b0, acc, 0, 0, 0);
        acc = __builtin_amdgcn_mfma_f32_16x16x32_bf16(a1, b1, acc, 0, 0, 0);
        int cls = cls0 + cl;
        if (cls < NCLS) {
          float bc = bcls[cls];
          #pragma unroll
          for (int r = 0; r < 4; ++r) {
            int t = q * 4 + r;
            out[((size_t)(b * TSEQ + tb + t)) * NCLS + cls] = acc[r] + bc;
          }
        }
      }
    }
  }
}

// ---------------------------------------------------------------------------
extern "C" void kernel_launch(void* const* d_in, const int* in_sizes, int n_in,
                              void* d_out, int out_size, void* d_ws, size_t ws_size,
                              hipStream_t stream) {
  (void)in_sizes; (void)n_in; (void)out_size; (void)ws_size;
  const float* x     = (const float*)d_in[0];
  const float* ln0g  = (const float*)d_in[1];
  const float* ln0b  = (const float*)d_in[2];
  const float* Wemb  = (const float*)d_in[3];
  const float* bemb  = (const float*)d_in[4];
  const float* lng   = (const float*)d_in[5];
  const float* lnb   = (const float*)d_in[6];
  const float* nulog = (const float*)d_in[7];
  const float* thlog = (const float*)d_in[8];
  const float* gmlog = (const float*)d_in[9];
  const float* Bre   = (const float*)d_in[10];
  const float* Bim   = (const float*)d_in[11];
  const float* Cre   = (const float*)d_in[12];
  const float* Cim   = (const float*)d_in[13];
  const float* dskip = (const float*)d_in[14];
  const float* Wcls  = (const float*)d_in[15];
  const float* bcls  = (const float*)d_in[16];
  float* out = (float*)d_out;

  char* ws = (char*)d_ws;
  // ws layout (bytes):
  //  carrA @0       : 8*32*256*4 = 262144
  //  carrB @262144  : 262144
  //  Bws   @524288  : 20*256*64*2 = 655360
  //  Cws   @1179648 : 655360
  //  Wt    @1835008 : 64*2048*2  = 262144
  //  Wclst @2097152 : 208*64*2   = 26624
  //  h0    @2123776 : 16384*64*4 = 4194304   (end 6318080)
  float* carrA         = (float*)(ws + 0);
  float* carrB         = (float*)(ws + 262144);
  unsigned short* Bws  = (unsigned short*)(ws + 524288);
  unsigned short* Cws  = (unsigned short*)(ws + 1179648);
  unsigned short* Wt   = (unsigned short*)(ws + 1835008);
  unsigned short* Wcl  = (unsigned short*)(ws + 2097152);
  float* h0            = (float*)(ws + 2123776);

  lru_convert_kernel<<<3124, 256, 0, stream>>>(Wemb, Bre, Bim, Cre, Cim, Wcls,
                                               Wt, Bws, Cws, Wcl);
  lru_embed_kernel<<<1024, 256, 0, stream>>>(x, ln0g, ln0b, Wt, bemb, h0);
  lru_carry0_kernel<<<256, 256, 0, stream>>>(h0, Bws, lng, lnb,
                                             nulog, thlog, gmlog, carrA);
  for (int s = 0; s < NSTAGE; ++s) {
    float* cin  = (s & 1) ? carrB : carrA;
    float* cout = (s & 1) ? carrA : carrB;
    lru_applycarry_kernel<<<256, 256, 0, stream>>>(h0, cin, cout, Bws, Cws,
                                                   lng, lnb, nulog, thlog,
                                                   gmlog, dskip, s,
                                                   (s == NSTAGE - 1) ? 1 : 0,
                                                   Wcl, bcls, out);
  }
}